// Round 7
// baseline (735.614 us; speedup 1.0000x reference)
//
#include <hip/hip_runtime.h>
#include <hip/hip_bf16.h>

#define NROWS 16384
#define NCODES 8192
#define DIM 256
#define BM 128                     // rows per block
#define SPLITS 2
#define CPB (NCODES / SPLITS)      // 4096 codes per block
#define CAP 24
#define MARGIND 1.7e-4f            // dot-scale margin (validated round 3)

#define WFRAG_BLOCKS 1024          // 8192*256/8 / 256
#define SQ_BLOCKS 1536             // (16384+8192) rows / 16 per block

typedef __attribute__((ext_vector_type(8))) short bf16x8;
typedef __attribute__((ext_vector_type(4))) float f32x4;

__device__ inline unsigned short f2bf(float f) {
    union { __hip_bfloat16 h; unsigned short u; } cv;
    cv.h = __float2bfloat16(f);
    return cv.u;
}
__device__ inline unsigned f2ord(float f) {
    unsigned u = __float_as_uint(f);
    return u ^ ((u >> 31) ? 0xFFFFFFFFu : 0x80000000u);
}
__device__ inline float ord2f(unsigned u) {
    unsigned v = (u & 0x80000000u) ? (u ^ 0x80000000u) : ~u;
    return __uint_as_float(v);
}

// Fused prep (validated rounds 1-6, absmax 0.0):
//  blocks [0, WFRAG_BLOCKS): pre-swizzle W into MFMA fragment order (bf16),
//    c16-major: flat unit tid = (c16*8 + k32)*64 + L holds 8 bf16 =
//      W[c16*16 + (L&15)][k32*32 + (L>>4)*8 + j]
//  blocks [WFRAG_BLOCKS, +SQ_BLOCKS): xsq/wsq via the EXACT pairwise256 tree,
//    16 lanes/row, shfl-xor combine (bit-exact; fp add operand-commutative).
//    Also initializes best64g.
__global__ __launch_bounds__(256)
void prep_kernel(const float* __restrict__ x, const float* __restrict__ w,
                 unsigned short* __restrict__ whf,
                 float* __restrict__ xsq, float* __restrict__ wsq,
                 unsigned long long* __restrict__ best64g) {
    if (blockIdx.x < WFRAG_BLOCKS) {
        int tid = blockIdx.x * 256 + threadIdx.x;   // 0 .. 262143
        int L = tid & 63;
        int rest = tid >> 6;
        int k32 = rest & 7;
        int c16 = rest >> 3;
        int code = c16 * 16 + (L & 15);
        int k = k32 * 32 + (L >> 4) * 8;
        const float4* p = reinterpret_cast<const float4*>(w + (size_t)code * DIM + k);
        float4 u0 = p[0], u1 = p[1];
        unsigned short tmp[8];
        tmp[0] = f2bf(u0.x); tmp[1] = f2bf(u0.y); tmp[2] = f2bf(u0.z); tmp[3] = f2bf(u0.w);
        tmp[4] = f2bf(u1.x); tmp[5] = f2bf(u1.y); tmp[6] = f2bf(u1.z); tmp[7] = f2bf(u1.w);
        *reinterpret_cast<uint4*>(whf + (size_t)tid * 8) = *reinterpret_cast<uint4*>(tmp);
    } else {
        int blk = blockIdx.x - WFRAG_BLOCKS;
        int row = blk * 16 + (threadIdx.x >> 4);     // 0 .. 24575
        int c = threadIdx.x & 15;
        int j = c & 7, h = c >> 3;
        const float* src = (row < NROWS) ? (x + (size_t)row * DIM)
                                         : (w + (size_t)(row - NROWS) * DIM);
        const float* base = src + h * 128 + j;
        float r = 0.0f;
        #pragma unroll
        for (int g = 0; g < 16; ++g) {
            float v = base[g * 8];
            r = __fadd_rn(r, __fmul_rn(v, v));
        }
        float t;
        t = __shfl_xor(r, 1, 64); r = __fadd_rn(r, t);
        t = __shfl_xor(r, 2, 64); r = __fadd_rn(r, t);
        t = __shfl_xor(r, 4, 64); r = __fadd_rn(r, t);
        t = __shfl_xor(r, 8, 64); r = __fadd_rn(r, t);
        if (c == 0) {
            if (row < NROWS) xsq[row] = r;
            else wsq[row - NROWS] = r;
        }
        if (c == 1 && row < NROWS) best64g[row] = 0xFFFFFFFFFFFFFFFFULL;
    }
}

// Main, round 7: CODE-SIZE. MfmaUtil x dur is constant across r0-r6 and
// tracks MFMA-per-instruction-executed => instruction-fetch-bound theory
// (fully-unrolled pass loop ~40+ KB exceeds I-cache; ~150 cyc/instr
// effective). Fix: r3's exact geometry (512 thr, BM=128, acc[8][4],
// 32-MFMA clusters, SPLITS=2, grid 256 -- proven 158 us) with the hot
// loops kept as REAL loops: #pragma unroll 1 on pass loop and k-loop
// (2-step body for static double-buffer names). Hot code ~5 KB, one copy.
// Numerics identical to r3 (validated); r5 determinism fallback retained.
__global__ __launch_bounds__(512, 2)
void vq_main(const float* __restrict__ x, const float* __restrict__ w,
             const unsigned short* __restrict__ whf,
             const float* __restrict__ wsq, const float* __restrict__ xsq,
             unsigned long long* __restrict__ best64g) {
    __shared__ unsigned short afrag[8 * 8 * 64 * 8];   // rg,k32,lane -> 16B frag; 64 KB
    __shared__ unsigned rowmax[BM];                    // ordered-uint max of dot
    __shared__ int cnt[BM];
    __shared__ int cand[BM][CAP];
    __shared__ int ovf_list[BM];
    __shared__ int ovf_n;

    const int tid = threadIdx.x;
    const int lane = tid & 63;
    const int wv = tid >> 6;          // 0..7
    const int lm = lane & 15;
    const int lq = lane >> 4;

    // block -> (split, rowGroup); same-split blocks cluster per XCD (L2 locality)
    const int blk = blockIdx.x;
    const int xcd = blk & 7;
    const int split = xcd & 1;
    const int rowGroup = (xcd >> 1) * 32 + (blk >> 3);   // bijective 0..127 per split
    const int rowBase = rowGroup * BM;
    const int codeBase = split * CPB;
    const int codeBase16 = codeBase >> 4;                // c16 units

    if (tid < BM) { rowmax[tid] = 0u; cnt[tid] = 0; }
    if (tid == 0) ovf_n = 0;

    // ---- stage A tile once (bf16, fragment order); wave wv stages rg=wv ----
    {
        const int rg = wv;
        const float* xr = x + (size_t)(rowBase + rg * 16 + lm) * DIM + lq * 8;
        #pragma unroll
        for (int k32 = 0; k32 < 8; ++k32) {
            float4 u0 = *reinterpret_cast<const float4*>(xr + k32 * 32);
            float4 u1 = *reinterpret_cast<const float4*>(xr + k32 * 32 + 4);
            unsigned short t8[8];
            t8[0] = f2bf(u0.x); t8[1] = f2bf(u0.y); t8[2] = f2bf(u0.z); t8[3] = f2bf(u0.w);
            t8[4] = f2bf(u1.x); t8[5] = f2bf(u1.y); t8[6] = f2bf(u1.z); t8[7] = f2bf(u1.w);
            *reinterpret_cast<uint4*>(afrag + ((rg * 8 + k32) * 64 + lane) * 8) =
                *reinterpret_cast<uint4*>(t8);
        }
    }
    __syncthreads();   // the ONLY barrier before the final reduction

    const unsigned short* afb = afrag + (size_t)lane * 8;   // ds_reads: afb + offset
    const int waveCode16 = codeBase16 + wv * 32;            // base c16 for this wave

    #pragma unroll 1
    for (int p = 0; p < 8; ++p) {                      // 8 passes x 64 codes
        const int pbase16 = waveCode16 + p * 4;
        const unsigned short* wpass = whf + (size_t)pbase16 * 4096 + lane * 8;

        f32x4 acc[8][4];
        #pragma unroll
        for (int rg = 0; rg < 8; ++rg)
            #pragma unroll
            for (int cf = 0; cf < 4; ++cf)
                acc[rg][cf] = (f32x4){0.f, 0.f, 0.f, 0.f};

        bf16x8 bbA[4], bbB[4];
        #pragma unroll
        for (int cf = 0; cf < 4; ++cf)
            bbA[cf] = *reinterpret_cast<const bf16x8*>(wpass + cf * 4096);

        #pragma unroll 1
        for (int k = 0; k < 8; k += 2) {
            // ---- half A: consume bbA (k), prefetch bbB (k+1) ----
            #pragma unroll
            for (int cf = 0; cf < 4; ++cf)
                bbB[cf] = *reinterpret_cast<const bf16x8*>(
                    wpass + cf * 4096 + (k + 1) * 512);
            bf16x8 aA[8];
            #pragma unroll
            for (int rg = 0; rg < 8; ++rg)
                aA[rg] = *reinterpret_cast<const bf16x8*>(afb + (rg * 8 + k) * 512);
            #pragma unroll
            for (int cf = 0; cf < 4; ++cf)
                #pragma unroll
                for (int rg = 0; rg < 8; ++rg)
                    acc[rg][cf] = __builtin_amdgcn_mfma_f32_16x16x32_bf16(
                        bbA[cf], aA[rg], acc[rg][cf], 0, 0, 0);
            // ---- half B: consume bbB (k+1), prefetch bbA (k+2) ----
            // k=6 prefetches slice 8 = first 1 KB of the next c16: in-bounds
            // of the 4 MB whf for every block (max c16 touched < 512); unused.
            #pragma unroll
            for (int cf = 0; cf < 4; ++cf)
                bbA[cf] = *reinterpret_cast<const bf16x8*>(
                    wpass + cf * 4096 + (k + 2) * 512);
            bf16x8 aB[8];
            #pragma unroll
            for (int rg = 0; rg < 8; ++rg)
                aB[rg] = *reinterpret_cast<const bf16x8*>(afb + (rg * 8 + k + 1) * 512);
            #pragma unroll
            for (int cf = 0; cf < 4; ++cf)
                #pragma unroll
                for (int rg = 0; rg < 8; ++rg)
                    acc[rg][cf] = __builtin_amdgcn_mfma_f32_16x16x32_bf16(
                        bbB[cf], aB[rg], acc[rg][cf], 0, 0, 0);
        }

        // ---- epilogue: track max dot per row; candidates = prefix-max superset
        #pragma unroll
        for (int rg = 0; rg < 8; ++rg) {
            float m = -__builtin_huge_valf();
            #pragma unroll
            for (int cf = 0; cf < 4; ++cf)
                #pragma unroll
                for (int r = 0; r < 4; ++r)
                    m = fmaxf(m, acc[rg][cf][r]);
            float rm = fmaxf(m, __shfl_xor(m, 16, 64));
            rm = fmaxf(rm, __shfl_xor(rm, 32, 64));
            const int row = rg * 16 + lm;
            if (lq == 0) atomicMax(&rowmax[row], f2ord(rm));
            // own wave's atomic lands before this read (in-order DS per wave);
            // stale (smaller) cross-wave max => lower limit => superset, safe
            float limit = ord2f(rowmax[row]) - MARGIND;
            if (m >= limit) {
                #pragma unroll
                for (int cf = 0; cf < 4; ++cf)
                    #pragma unroll
                    for (int r = 0; r < 4; ++r) {
                        if (acc[rg][cf][r] >= limit) {
                            int pos = atomicAdd(&cnt[row], 1);
                            if (pos < CAP)
                                cand[row][pos] = (pbase16 + cf) * 16 + lq * 4 + r;
                        }
                    }
            }
        }
    }
    __syncthreads();

    // rows whose candidate list overflowed (dropped entries depend on atomic
    // ordering) get a deterministic full-split exact rescan below
    if (tid < BM && cnt[tid] > CAP) {
        int i = atomicAdd(&ovf_n, 1);
        ovf_list[i] = tid;
    }
    __syncthreads();

    // ---- exact rescore (bit-identical validated formula, f32, incl. wsq) ----
    #pragma unroll 1
    for (int slot = tid; slot < BM * CAP; slot += 512) {
        int row = slot / CAP, pos = slot - (slot / CAP) * CAP;
        int n = cnt[row] < CAP ? cnt[row] : CAP;
        if (pos < n) {
            int c = cand[row][pos];
            const float* xr = x + (size_t)(rowBase + row) * DIM;
            const float* wr = w + (size_t)c * DIM;
            float d = 0.f;
            #pragma unroll 1
            for (int k = 0; k < DIM; k += 4) {
                float4 a = *reinterpret_cast<const float4*>(xr + k);
                float4 b = *reinterpret_cast<const float4*>(wr + k);
                d = fmaf(a.x, b.x, d);
                d = fmaf(a.y, b.y, d);
                d = fmaf(a.z, b.z, d);
                d = fmaf(a.w, b.w, d);
            }
            float t1 = __fadd_rn(xsq[rowBase + row], wsq[c]);
            float s = __fsub_rn(t1, __fadd_rn(d, d));
            unsigned long long key =
                ((unsigned long long)__float_as_uint(s) << 32) | (unsigned)c;
            atomicMin(best64g + rowBase + row, key);   // s>0: bit order = float order
        }
    }

    // ---- overflow fallback: one wave per row, full exact scan of this
    //      block's code split (same formula => identical keys) ----
    #pragma unroll 1
    for (int i = wv; i < ovf_n; i += 8) {
        const int row = ovf_list[i];
        const float* xr = x + (size_t)(rowBase + row) * DIM;
        const float xq = xsq[rowBase + row];
        unsigned long long best = 0xFFFFFFFFFFFFFFFFULL;
        #pragma unroll 1
        for (int t = lane; t < CPB; t += 64) {
            int c = codeBase + t;
            const float* wr = w + (size_t)c * DIM;
            float d = 0.f;
            #pragma unroll 1
            for (int k = 0; k < DIM; k += 4) {
                float4 a4 = *reinterpret_cast<const float4*>(xr + k);
                float4 b4 = *reinterpret_cast<const float4*>(wr + k);
                d = fmaf(a4.x, b4.x, d);
                d = fmaf(a4.y, b4.y, d);
                d = fmaf(a4.z, b4.z, d);
                d = fmaf(a4.w, b4.w, d);
            }
            float t1 = __fadd_rn(xq, wsq[c]);
            float s = __fsub_rn(t1, __fadd_rn(d, d));
            unsigned long long key =
                ((unsigned long long)__float_as_uint(s) << 32) | (unsigned)c;
            best = best < key ? best : key;
        }
        #pragma unroll
        for (int msk = 32; msk >= 1; msk >>= 1) {
            unsigned long long o = __shfl_xor(best, msk, 64);
            best = best < o ? best : o;
        }
        if (lane == 0) atomicMin(best64g + rowBase + row, best);
    }
}

// Final: read per-row best key, write index + gather codeword.
__global__ __launch_bounds__(256)
void out_kernel(const float* __restrict__ w,
                const unsigned long long* __restrict__ best64g,
                float* __restrict__ out_q, float* __restrict__ out_idx) {
    int r = blockIdx.x * 4 + (threadIdx.x >> 6);
    int lane = threadIdx.x & 63;
    unsigned long long key = best64g[r];
    int idx = (int)(key & 0xFFFFFFFFu);
    float4 v = reinterpret_cast<const float4*>(w + (size_t)idx * DIM)[lane];
    reinterpret_cast<float4*>(out_q + (size_t)r * DIM)[lane] = v;
    if (lane == 0) out_idx[r] = (float)idx;
}

extern "C" void kernel_launch(void* const* d_in, const int* in_sizes, int n_in,
                              void* d_out, int out_size, void* d_ws, size_t ws_size,
                              hipStream_t stream) {
    const float* x = (const float*)d_in[0];   // (16384, 256) fp32
    const float* w = (const float*)d_in[1];   // (8192, 256) fp32
    float* out_q = (float*)d_out;
    float* out_idx = (float*)d_out + (size_t)NROWS * DIM;

    unsigned short* whf = (unsigned short*)d_ws;                      // 4 MB
    float* wsq = (float*)((char*)d_ws + (size_t)NCODES * DIM * 2);    // 32 KB
    float* xsq = wsq + NCODES;                                        // 64 KB
    unsigned long long* best64g = (unsigned long long*)(xsq + NROWS); // 128 KB

    prep_kernel<<<WFRAG_BLOCKS + SQ_BLOCKS, 256, 0, stream>>>(x, w, whf, xsq, wsq, best64g);
    vq_main<<<(NROWS / BM) * SPLITS, 512, 0, stream>>>(x, w, whf, wsq, xsq, best64g);
    out_kernel<<<NROWS / 4, 256, 0, stream>>>(w, best64g, out_q, out_idx);
}

// Round 8
// 683.433 us; speedup vs baseline: 1.0764x; 1.0764x over previous
//
#include <hip/hip_runtime.h>
#include <hip/hip_bf16.h>

#define NROWS 16384
#define NCODES 8192
#define DIM 256
#define BM 128                     // rows per block
#define SPLITS 2
#define CPB (NCODES / SPLITS)      // 4096 codes per block
#define CAP 24
#define MARGIND 1.7e-4f            // dot-scale margin (validated round 3)

#define WFRAG_BLOCKS 1024          // 8192*256/8 / 256
#define SQ_BLOCKS 1536             // (16384+8192) rows / 16 per block

typedef __attribute__((ext_vector_type(8))) short bf16x8;
typedef __attribute__((ext_vector_type(4))) float f32x4;

__device__ inline unsigned short f2bf(float f) {
    union { __hip_bfloat16 h; unsigned short u; } cv;
    cv.h = __float2bfloat16(f);
    return cv.u;
}
__device__ inline unsigned f2ord(float f) {
    unsigned u = __float_as_uint(f);
    return u ^ ((u >> 31) ? 0xFFFFFFFFu : 0x80000000u);
}
__device__ inline float ord2f(unsigned u) {
    unsigned v = (u & 0x80000000u) ? (u ^ 0x80000000u) : ~u;
    return __uint_as_float(v);
}

// async global->LDS, 16B per lane; LDS dest is wave-uniform base + lane*16.
__device__ inline void gload16(const unsigned short* g, unsigned short* l) {
    __builtin_amdgcn_global_load_lds(
        (__attribute__((address_space(1))) void*)g,
        (__attribute__((address_space(3))) void*)l, 16, 0, 0);
}

// Fused prep (validated rounds 1-7, absmax 0.0):
//  blocks [0, WFRAG_BLOCKS): pre-swizzle W into MFMA fragment order (bf16),
//    c16-major: flat unit tid = (c16*8 + k32)*64 + L holds 8 bf16 =
//      W[c16*16 + (L&15)][k32*32 + (L>>4)*8 + j]
//  blocks [WFRAG_BLOCKS, +SQ_BLOCKS): xsq/wsq via the EXACT pairwise256 tree,
//    16 lanes/row, shfl-xor combine (bit-exact; fp add operand-commutative).
//    Also initializes best64g.
__global__ __launch_bounds__(256)
void prep_kernel(const float* __restrict__ x, const float* __restrict__ w,
                 unsigned short* __restrict__ whf,
                 float* __restrict__ xsq, float* __restrict__ wsq,
                 unsigned long long* __restrict__ best64g) {
    if (blockIdx.x < WFRAG_BLOCKS) {
        int tid = blockIdx.x * 256 + threadIdx.x;   // 0 .. 262143
        int L = tid & 63;
        int rest = tid >> 6;
        int k32 = rest & 7;
        int c16 = rest >> 3;
        int code = c16 * 16 + (L & 15);
        int k = k32 * 32 + (L >> 4) * 8;
        const float4* p = reinterpret_cast<const float4*>(w + (size_t)code * DIM + k);
        float4 u0 = p[0], u1 = p[1];
        unsigned short tmp[8];
        tmp[0] = f2bf(u0.x); tmp[1] = f2bf(u0.y); tmp[2] = f2bf(u0.z); tmp[3] = f2bf(u0.w);
        tmp[4] = f2bf(u1.x); tmp[5] = f2bf(u1.y); tmp[6] = f2bf(u1.z); tmp[7] = f2bf(u1.w);
        *reinterpret_cast<uint4*>(whf + (size_t)tid * 8) = *reinterpret_cast<uint4*>(tmp);
    } else {
        int blk = blockIdx.x - WFRAG_BLOCKS;
        int row = blk * 16 + (threadIdx.x >> 4);     // 0 .. 24575
        int c = threadIdx.x & 15;
        int j = c & 7, h = c >> 3;
        const float* src = (row < NROWS) ? (x + (size_t)row * DIM)
                                         : (w + (size_t)(row - NROWS) * DIM);
        const float* base = src + h * 128 + j;
        float r = 0.0f;
        #pragma unroll
        for (int g = 0; g < 16; ++g) {
            float v = base[g * 8];
            r = __fadd_rn(r, __fmul_rn(v, v));
        }
        float t;
        t = __shfl_xor(r, 1, 64); r = __fadd_rn(r, t);
        t = __shfl_xor(r, 2, 64); r = __fadd_rn(r, t);
        t = __shfl_xor(r, 4, 64); r = __fadd_rn(r, t);
        t = __shfl_xor(r, 8, 64); r = __fadd_rn(r, t);
        if (c == 0) {
            if (row < NROWS) xsq[row] = r;
            else wsq[row - NROWS] = r;
        }
        if (c == 1 && row < NROWS) best64g[row] = 0xFFFFFFFFFFFFFFFFULL;
    }
}

// Main, round 8: COUNTED-VMCNT PIPELINE. r7 proved the stall is exposed
// vmem latency at each wait point (unroll-1 serialized waits -> 4.2x slower;
// r5/r6 more wait points -> worse). Fix: r3's exact geometry + numerics, but
// the B (codes) path becomes a wave-PRIVATE LDS double buffer staged with
// global_load_lds (4 x 16B/lane = 4KB per wave per k-step) and an explicit
// s_waitcnt vmcnt(4): the previous step's stage is guaranteed done while the
// current stage stays in flight. vmcnt never drains in the loop, no barriers
// (regions are wave-private), no other vmem ops in the loop so the count is
// exact. Prefetch distance = one k-step >> 900cyc HBM-miss latency.
__global__ __launch_bounds__(512, 2)
void vq_main(const float* __restrict__ x, const float* __restrict__ w,
             const unsigned short* __restrict__ whf,
             const float* __restrict__ wsq, const float* __restrict__ xsq,
             unsigned long long* __restrict__ best64g) {
    __shared__ unsigned short afrag[8 * 8 * 64 * 8];   // rows: 64 KB
    __shared__ unsigned short bstage[2 * 8 * 4 * 64 * 8]; // codes dbuf: 64 KB
    __shared__ unsigned rowmax[BM];                    // ordered-uint max of dot
    __shared__ int cnt[BM];
    __shared__ int cand[BM][CAP];
    __shared__ int ovf_list[BM];
    __shared__ int ovf_n;

    const int tid = threadIdx.x;
    const int lane = tid & 63;
    const int wv = tid >> 6;          // 0..7
    const int lm = lane & 15;
    const int lq = lane >> 4;

    // block -> (split, rowGroup); same-split blocks cluster per XCD (L2 locality)
    const int blk = blockIdx.x;
    const int xcd = blk & 7;
    const int split = xcd & 1;
    const int rowGroup = (xcd >> 1) * 32 + (blk >> 3);   // bijective 0..127 per split
    const int rowBase = rowGroup * BM;
    const int codeBase = split * CPB;
    const int codeBase16 = codeBase >> 4;                // c16 units
    const int waveCode16 = codeBase16 + wv * 32;         // base c16 for this wave

    if (tid < BM) { rowmax[tid] = 0u; cnt[tid] = 0; }
    if (tid == 0) ovf_n = 0;

    // wave-private staging region: bstage[buf][wv][cf][lane*8]
    unsigned short* bpriv = bstage + wv * 2048;          // +buf*16384 +cf*512

    // ---- prologue: stage (p=0,s=0) into buffer 0 (latency hides under afrag) ----
    {
        const unsigned short* src =
            whf + (size_t)waveCode16 * 4096 + lane * 8;
        #pragma unroll
        for (int cf = 0; cf < 4; ++cf)
            gload16(src + cf * 4096, bpriv + cf * 512);
    }

    // ---- stage A tile once (bf16, fragment order); wave wv stages rg=wv ----
    {
        const int rg = wv;
        const float* xr = x + (size_t)(rowBase + rg * 16 + lm) * DIM + lq * 8;
        #pragma unroll
        for (int k32 = 0; k32 < 8; ++k32) {
            float4 u0 = *reinterpret_cast<const float4*>(xr + k32 * 32);
            float4 u1 = *reinterpret_cast<const float4*>(xr + k32 * 32 + 4);
            unsigned short t8[8];
            t8[0] = f2bf(u0.x); t8[1] = f2bf(u0.y); t8[2] = f2bf(u0.z); t8[3] = f2bf(u0.w);
            t8[4] = f2bf(u1.x); t8[5] = f2bf(u1.y); t8[6] = f2bf(u1.z); t8[7] = f2bf(u1.w);
            *reinterpret_cast<uint4*>(afrag + ((rg * 8 + k32) * 64 + lane) * 8) =
                *reinterpret_cast<uint4*>(t8);
        }
    }
    __syncthreads();   // drains vmcnt once (prologue stage completes; count resets)

    const unsigned short* afb = afrag + (size_t)lane * 8;   // ds_reads: afb + offset

    #pragma unroll 1
    for (int p = 0; p < 8; ++p) {                      // 8 passes x 64 codes
        const int pbase16 = waveCode16 + p * 4;

        f32x4 acc[8][4];
        #pragma unroll
        for (int rg = 0; rg < 8; ++rg)
            #pragma unroll
            for (int cf = 0; cf < 4; ++cf)
                acc[rg][cf] = (f32x4){0.f, 0.f, 0.f, 0.f};

        #pragma unroll 1
        for (int s = 0; s < 8; ++s) {
            const int g = p * 8 + s;
            if (g < 63) {
                // stage step g+1 into the other buffer (wave-private)
                const int gn = g + 1;
                const int pn = gn >> 3, sn = gn & 7;
                const unsigned short* src =
                    whf + (size_t)(waveCode16 + pn * 4) * 4096 + sn * 512 + lane * 8;
                unsigned short* dst = bpriv + ((s & 1) ^ 1) * 16384;
                #pragma unroll
                for (int cf = 0; cf < 4; ++cf)
                    gload16(src + cf * 4096, dst + cf * 512);
                asm volatile("s_waitcnt vmcnt(4)" ::: "memory");  // step g done
            } else {
                asm volatile("s_waitcnt vmcnt(0)" ::: "memory");  // last step
            }
            __builtin_amdgcn_sched_barrier(0);

            const unsigned short* bbase = bpriv + (s & 1) * 16384 + lane * 8;
            bf16x8 bb[4];
            #pragma unroll
            for (int cf = 0; cf < 4; ++cf)
                bb[cf] = *reinterpret_cast<const bf16x8*>(bbase + cf * 512);
            bf16x8 a[8];
            #pragma unroll
            for (int rg = 0; rg < 8; ++rg)
                a[rg] = *reinterpret_cast<const bf16x8*>(afb + (rg * 8 + s) * 512);
            // A = codes (bb), B = rows (a). C: col=row(lm), row=code.
            #pragma unroll
            for (int cf = 0; cf < 4; ++cf)
                #pragma unroll
                for (int rg = 0; rg < 8; ++rg)
                    acc[rg][cf] = __builtin_amdgcn_mfma_f32_16x16x32_bf16(
                        bb[cf], a[rg], acc[rg][cf], 0, 0, 0);
        }

        // ---- epilogue: track max dot per row; candidates = prefix-max superset
        #pragma unroll
        for (int rg = 0; rg < 8; ++rg) {
            float m = -__builtin_huge_valf();
            #pragma unroll
            for (int cf = 0; cf < 4; ++cf)
                #pragma unroll
                for (int r = 0; r < 4; ++r)
                    m = fmaxf(m, acc[rg][cf][r]);
            float rm = fmaxf(m, __shfl_xor(m, 16, 64));
            rm = fmaxf(rm, __shfl_xor(rm, 32, 64));
            const int row = rg * 16 + lm;
            if (lq == 0) atomicMax(&rowmax[row], f2ord(rm));
            // own wave's atomic lands before this read (in-order DS per wave);
            // stale (smaller) cross-wave max => lower limit => superset, safe
            float limit = ord2f(rowmax[row]) - MARGIND;
            if (m >= limit) {
                #pragma unroll
                for (int cf = 0; cf < 4; ++cf)
                    #pragma unroll
                    for (int r = 0; r < 4; ++r) {
                        if (acc[rg][cf][r] >= limit) {
                            int pos = atomicAdd(&cnt[row], 1);
                            if (pos < CAP)
                                cand[row][pos] = (pbase16 + cf) * 16 + lq * 4 + r;
                        }
                    }
            }
        }
    }
    __syncthreads();

    // rows whose candidate list overflowed (dropped entries depend on atomic
    // ordering) get a deterministic full-split exact rescan below
    if (tid < BM && cnt[tid] > CAP) {
        int i = atomicAdd(&ovf_n, 1);
        ovf_list[i] = tid;
    }
    __syncthreads();

    // ---- exact rescore (bit-identical validated formula, f32, incl. wsq) ----
    #pragma unroll 1
    for (int slot = tid; slot < BM * CAP; slot += 512) {
        int row = slot / CAP, pos = slot - (slot / CAP) * CAP;
        int n = cnt[row] < CAP ? cnt[row] : CAP;
        if (pos < n) {
            int c = cand[row][pos];
            const float* xr = x + (size_t)(rowBase + row) * DIM;
            const float* wr = w + (size_t)c * DIM;
            float d = 0.f;
            #pragma unroll 1
            for (int k = 0; k < DIM; k += 4) {
                float4 a = *reinterpret_cast<const float4*>(xr + k);
                float4 b = *reinterpret_cast<const float4*>(wr + k);
                d = fmaf(a.x, b.x, d);
                d = fmaf(a.y, b.y, d);
                d = fmaf(a.z, b.z, d);
                d = fmaf(a.w, b.w, d);
            }
            float t1 = __fadd_rn(xsq[rowBase + row], wsq[c]);
            float s = __fsub_rn(t1, __fadd_rn(d, d));
            unsigned long long key =
                ((unsigned long long)__float_as_uint(s) << 32) | (unsigned)c;
            atomicMin(best64g + rowBase + row, key);   // s>0: bit order = float order
        }
    }

    // ---- overflow fallback: one wave per row, full exact scan of this
    //      block's code split (same formula => identical keys) ----
    #pragma unroll 1
    for (int i = wv; i < ovf_n; i += 8) {
        const int row = ovf_list[i];
        const float* xr = x + (size_t)(rowBase + row) * DIM;
        const float xq = xsq[rowBase + row];
        unsigned long long best = 0xFFFFFFFFFFFFFFFFULL;
        #pragma unroll 1
        for (int t = lane; t < CPB; t += 64) {
            int c = codeBase + t;
            const float* wr = w + (size_t)c * DIM;
            float d = 0.f;
            #pragma unroll 1
            for (int k = 0; k < DIM; k += 4) {
                float4 a4 = *reinterpret_cast<const float4*>(xr + k);
                float4 b4 = *reinterpret_cast<const float4*>(wr + k);
                d = fmaf(a4.x, b4.x, d);
                d = fmaf(a4.y, b4.y, d);
                d = fmaf(a4.z, b4.z, d);
                d = fmaf(a4.w, b4.w, d);
            }
            float t1 = __fadd_rn(xq, wsq[c]);
            float s = __fsub_rn(t1, __fadd_rn(d, d));
            unsigned long long key =
                ((unsigned long long)__float_as_uint(s) << 32) | (unsigned)c;
            best = best < key ? best : key;
        }
        #pragma unroll
        for (int msk = 32; msk >= 1; msk >>= 1) {
            unsigned long long o = __shfl_xor(best, msk, 64);
            best = best < o ? best : o;
        }
        if (lane == 0) atomicMin(best64g + rowBase + row, best);
    }
}

// Final: read per-row best key, write index + gather codeword.
__global__ __launch_bounds__(256)
void out_kernel(const float* __restrict__ w,
                const unsigned long long* __restrict__ best64g,
                float* __restrict__ out_q, float* __restrict__ out_idx) {
    int r = blockIdx.x * 4 + (threadIdx.x >> 6);
    int lane = threadIdx.x & 63;
    unsigned long long key = best64g[r];
    int idx = (int)(key & 0xFFFFFFFFu);
    float4 v = reinterpret_cast<const float4*>(w + (size_t)idx * DIM)[lane];
    reinterpret_cast<float4*>(out_q + (size_t)r * DIM)[lane] = v;
    if (lane == 0) out_idx[r] = (float)idx;
}

extern "C" void kernel_launch(void* const* d_in, const int* in_sizes, int n_in,
                              void* d_out, int out_size, void* d_ws, size_t ws_size,
                              hipStream_t stream) {
    const float* x = (const float*)d_in[0];   // (16384, 256) fp32
    const float* w = (const float*)d_in[1];   // (8192, 256) fp32
    float* out_q = (float*)d_out;
    float* out_idx = (float*)d_out + (size_t)NROWS * DIM;

    unsigned short* whf = (unsigned short*)d_ws;                      // 4 MB
    float* wsq = (float*)((char*)d_ws + (size_t)NCODES * DIM * 2);    // 32 KB
    float* xsq = wsq + NCODES;                                        // 64 KB
    unsigned long long* best64g = (unsigned long long*)(xsq + NROWS); // 128 KB

    prep_kernel<<<WFRAG_BLOCKS + SQ_BLOCKS, 256, 0, stream>>>(x, w, whf, xsq, wsq, best64g);
    vq_main<<<(NROWS / BM) * SPLITS, 512, 0, stream>>>(x, w, whf, wsq, xsq, best64g);
    out_kernel<<<NROWS / 4, 256, 0, stream>>>(w, best64g, out_q, out_idx);
}

// Round 9
// 253.834 us; speedup vs baseline: 2.8980x; 2.6924x over previous
//
#include <hip/hip_runtime.h>
#include <hip/hip_bf16.h>

#define NROWS 16384
#define NCODES 8192
#define DIM 256
#define BM 128                     // rows per block
#define SPLITS 2
#define CPB (NCODES / SPLITS)      // 4096 codes per block
#define CAP 32
#define MARGIND 1.7e-4f            // dot-scale margin (validated round 3)

#define WFRAG_BLOCKS 1024          // 8192*256/8 / 256
#define SQ_BLOCKS 1536             // (16384+8192) rows / 16 per block

typedef __attribute__((ext_vector_type(8))) short bf16x8;
typedef __attribute__((ext_vector_type(4))) float f32x4;

__device__ inline unsigned short f2bf(float f) {
    union { __hip_bfloat16 h; unsigned short u; } cv;
    cv.h = __float2bfloat16(f);
    return cv.u;
}
__device__ inline unsigned f2ord(float f) {
    unsigned u = __float_as_uint(f);
    return u ^ ((u >> 31) ? 0xFFFFFFFFu : 0x80000000u);
}
__device__ inline float ord2f(unsigned u) {
    unsigned v = (u & 0x80000000u) ? (u ^ 0x80000000u) : ~u;
    return __uint_as_float(v);
}

// async global->LDS, 16B per lane; LDS dest is wave-uniform base + lane*16.
__device__ inline void gload16(const unsigned short* g, unsigned short* l) {
    __builtin_amdgcn_global_load_lds(
        (__attribute__((address_space(1))) void*)g,
        (__attribute__((address_space(3))) void*)l, 16, 0, 0);
}

// Fused prep (validated rounds 1-8, absmax 0.0):
//  blocks [0, WFRAG_BLOCKS): pre-swizzle W into MFMA fragment order (bf16),
//    c16-major: flat unit tid = (c16*8 + k32)*64 + L holds 8 bf16 =
//      W[c16*16 + (L&15)][k32*32 + (L>>4)*8 + j]
//  blocks [WFRAG_BLOCKS, +SQ_BLOCKS): xsq/wsq via the EXACT pairwise256 tree,
//    16 lanes/row, shfl-xor combine (bit-exact; fp add operand-commutative).
//    Also initializes best64g.
__global__ __launch_bounds__(256)
void prep_kernel(const float* __restrict__ x, const float* __restrict__ w,
                 unsigned short* __restrict__ whf,
                 float* __restrict__ xsq, float* __restrict__ wsq,
                 unsigned long long* __restrict__ best64g) {
    if (blockIdx.x < WFRAG_BLOCKS) {
        int tid = blockIdx.x * 256 + threadIdx.x;   // 0 .. 262143
        int L = tid & 63;
        int rest = tid >> 6;
        int k32 = rest & 7;
        int c16 = rest >> 3;
        int code = c16 * 16 + (L & 15);
        int k = k32 * 32 + (L >> 4) * 8;
        const float4* p = reinterpret_cast<const float4*>(w + (size_t)code * DIM + k);
        float4 u0 = p[0], u1 = p[1];
        unsigned short tmp[8];
        tmp[0] = f2bf(u0.x); tmp[1] = f2bf(u0.y); tmp[2] = f2bf(u0.z); tmp[3] = f2bf(u0.w);
        tmp[4] = f2bf(u1.x); tmp[5] = f2bf(u1.y); tmp[6] = f2bf(u1.z); tmp[7] = f2bf(u1.w);
        *reinterpret_cast<uint4*>(whf + (size_t)tid * 8) = *reinterpret_cast<uint4*>(tmp);
    } else {
        int blk = blockIdx.x - WFRAG_BLOCKS;
        int row = blk * 16 + (threadIdx.x >> 4);     // 0 .. 24575
        int c = threadIdx.x & 15;
        int j = c & 7, h = c >> 3;
        const float* src = (row < NROWS) ? (x + (size_t)row * DIM)
                                         : (w + (size_t)(row - NROWS) * DIM);
        const float* base = src + h * 128 + j;
        float r = 0.0f;
        #pragma unroll
        for (int g = 0; g < 16; ++g) {
            float v = base[g * 8];
            r = __fadd_rn(r, __fmul_rn(v, v));
        }
        float t;
        t = __shfl_xor(r, 1, 64); r = __fadd_rn(r, t);
        t = __shfl_xor(r, 2, 64); r = __fadd_rn(r, t);
        t = __shfl_xor(r, 4, 64); r = __fadd_rn(r, t);
        t = __shfl_xor(r, 8, 64); r = __fadd_rn(r, t);
        if (c == 0) {
            if (row < NROWS) xsq[row] = r;
            else wsq[row - NROWS] = r;
        }
        if (c == 1 && row < NROWS) best64g[row] = 0xFFFFFFFFFFFFFFFFULL;
    }
}

// Main, round 9: r8's counted-vmcnt pipeline UNCHANGED (its true cost was
// masked in r8 by the straggler fallback -- occupancy 5.6% proved ~80% of
// the 670us was a few blocks running the unroll-1 single-wave fallback at
// ~400us/row). Fixes this round: (1) fallback is cooperative -- all 512
// threads scan an overflowed row (8 codes/thread, 2 concurrent bit-identical
// serial-fmaf chains, wave-reduce, 1 atomic/wave => ~5us/row); (2) CAP 24->32
// (overflow rarer; +4KB LDS, still 1 block/CU); (3) rescore path back to
// default unrolling. Determinism: argmin always stored when cnt<=CAP;
// fallback exactly covers cnt>CAP; keys bit-identical across paths.
__global__ __launch_bounds__(512, 2)
void vq_main(const float* __restrict__ x, const float* __restrict__ w,
             const unsigned short* __restrict__ whf,
             const float* __restrict__ wsq, const float* __restrict__ xsq,
             unsigned long long* __restrict__ best64g) {
    __shared__ unsigned short afrag[8 * 8 * 64 * 8];      // rows: 64 KB
    __shared__ unsigned short bstage[2 * 8 * 4 * 64 * 8]; // codes dbuf: 64 KB
    __shared__ unsigned rowmax[BM];                       // ordered-uint max of dot
    __shared__ int cnt[BM];
    __shared__ int cand[BM][CAP];                         // 16 KB
    __shared__ int ovf_list[BM];
    __shared__ int ovf_n;

    const int tid = threadIdx.x;
    const int lane = tid & 63;
    const int wv = tid >> 6;          // 0..7
    const int lm = lane & 15;
    const int lq = lane >> 4;

    // block -> (split, rowGroup); same-split blocks cluster per XCD (L2 locality)
    const int blk = blockIdx.x;
    const int xcd = blk & 7;
    const int split = xcd & 1;
    const int rowGroup = (xcd >> 1) * 32 + (blk >> 3);   // bijective 0..127 per split
    const int rowBase = rowGroup * BM;
    const int codeBase = split * CPB;
    const int codeBase16 = codeBase >> 4;                // c16 units
    const int waveCode16 = codeBase16 + wv * 32;         // base c16 for this wave

    if (tid < BM) { rowmax[tid] = 0u; cnt[tid] = 0; }
    if (tid == 0) ovf_n = 0;

    // wave-private staging region: bstage[buf][wv][cf][lane*8]
    unsigned short* bpriv = bstage + wv * 2048;          // +buf*16384 +cf*512

    // ---- prologue: stage (p=0,s=0) into buffer 0 (latency hides under afrag) ----
    {
        const unsigned short* src =
            whf + (size_t)waveCode16 * 4096 + lane * 8;
        #pragma unroll
        for (int cf = 0; cf < 4; ++cf)
            gload16(src + cf * 4096, bpriv + cf * 512);
    }

    // ---- stage A tile once (bf16, fragment order); wave wv stages rg=wv ----
    {
        const int rg = wv;
        const float* xr = x + (size_t)(rowBase + rg * 16 + lm) * DIM + lq * 8;
        #pragma unroll
        for (int k32 = 0; k32 < 8; ++k32) {
            float4 u0 = *reinterpret_cast<const float4*>(xr + k32 * 32);
            float4 u1 = *reinterpret_cast<const float4*>(xr + k32 * 32 + 4);
            unsigned short t8[8];
            t8[0] = f2bf(u0.x); t8[1] = f2bf(u0.y); t8[2] = f2bf(u0.z); t8[3] = f2bf(u0.w);
            t8[4] = f2bf(u1.x); t8[5] = f2bf(u1.y); t8[6] = f2bf(u1.z); t8[7] = f2bf(u1.w);
            *reinterpret_cast<uint4*>(afrag + ((rg * 8 + k32) * 64 + lane) * 8) =
                *reinterpret_cast<uint4*>(t8);
        }
    }
    __syncthreads();   // drains vmcnt once (prologue stage completes; count resets)

    const unsigned short* afb = afrag + (size_t)lane * 8;   // ds_reads: afb + offset

    #pragma unroll 1
    for (int p = 0; p < 8; ++p) {                      // 8 passes x 64 codes
        const int pbase16 = waveCode16 + p * 4;

        f32x4 acc[8][4];
        #pragma unroll
        for (int rg = 0; rg < 8; ++rg)
            #pragma unroll
            for (int cf = 0; cf < 4; ++cf)
                acc[rg][cf] = (f32x4){0.f, 0.f, 0.f, 0.f};

        #pragma unroll 1
        for (int s = 0; s < 8; ++s) {
            const int g = p * 8 + s;
            if (g < 63) {
                // stage step g+1 into the other buffer (wave-private)
                const int gn = g + 1;
                const int pn = gn >> 3, sn = gn & 7;
                const unsigned short* src =
                    whf + (size_t)(waveCode16 + pn * 4) * 4096 + sn * 512 + lane * 8;
                unsigned short* dst = bpriv + ((s & 1) ^ 1) * 16384;
                #pragma unroll
                for (int cf = 0; cf < 4; ++cf)
                    gload16(src + cf * 4096, dst + cf * 512);
                asm volatile("s_waitcnt vmcnt(4)" ::: "memory");  // step g done
            } else {
                asm volatile("s_waitcnt vmcnt(0)" ::: "memory");  // last step
            }
            __builtin_amdgcn_sched_barrier(0);

            const unsigned short* bbase = bpriv + (s & 1) * 16384 + lane * 8;
            bf16x8 bb[4];
            #pragma unroll
            for (int cf = 0; cf < 4; ++cf)
                bb[cf] = *reinterpret_cast<const bf16x8*>(bbase + cf * 512);
            bf16x8 a[8];
            #pragma unroll
            for (int rg = 0; rg < 8; ++rg)
                a[rg] = *reinterpret_cast<const bf16x8*>(afb + (rg * 8 + s) * 512);
            // A = codes (bb), B = rows (a). C: col=row(lm), row=code.
            #pragma unroll
            for (int cf = 0; cf < 4; ++cf)
                #pragma unroll
                for (int rg = 0; rg < 8; ++rg)
                    acc[rg][cf] = __builtin_amdgcn_mfma_f32_16x16x32_bf16(
                        bb[cf], a[rg], acc[rg][cf], 0, 0, 0);
        }

        // ---- epilogue: track max dot per row; candidates = prefix-max superset
        #pragma unroll
        for (int rg = 0; rg < 8; ++rg) {
            float m = -__builtin_huge_valf();
            #pragma unroll
            for (int cf = 0; cf < 4; ++cf)
                #pragma unroll
                for (int r = 0; r < 4; ++r)
                    m = fmaxf(m, acc[rg][cf][r]);
            float rm = fmaxf(m, __shfl_xor(m, 16, 64));
            rm = fmaxf(rm, __shfl_xor(rm, 32, 64));
            const int row = rg * 16 + lm;
            if (lq == 0) atomicMax(&rowmax[row], f2ord(rm));
            // own wave's atomic lands before this read (in-order DS per wave);
            // stale (smaller) cross-wave max => lower limit => superset, safe
            float limit = ord2f(rowmax[row]) - MARGIND;
            if (m >= limit) {
                #pragma unroll
                for (int cf = 0; cf < 4; ++cf)
                    #pragma unroll
                    for (int r = 0; r < 4; ++r) {
                        if (acc[rg][cf][r] >= limit) {
                            int pos = atomicAdd(&cnt[row], 1);
                            if (pos < CAP)
                                cand[row][pos] = (pbase16 + cf) * 16 + lq * 4 + r;
                        }
                    }
            }
        }
    }
    __syncthreads();

    // rows whose candidate list overflowed (dropped entries depend on atomic
    // ordering) get a deterministic full-split exact rescan below
    if (tid < BM && cnt[tid] > CAP) {
        int i = atomicAdd(&ovf_n, 1);
        ovf_list[i] = tid;
    }
    __syncthreads();

    // ---- exact rescore (bit-identical validated formula, f32, incl. wsq) ----
    for (int slot = tid; slot < BM * CAP; slot += 512) {
        int row = slot / CAP, pos = slot - (slot / CAP) * CAP;
        int n = cnt[row] < CAP ? cnt[row] : CAP;
        if (pos < n) {
            int c = cand[row][pos];
            const float* xr = x + (size_t)(rowBase + row) * DIM;
            const float* wr = w + (size_t)c * DIM;
            float d = 0.f;
            for (int k = 0; k < DIM; k += 4) {
                float4 a = *reinterpret_cast<const float4*>(xr + k);
                float4 b = *reinterpret_cast<const float4*>(wr + k);
                d = fmaf(a.x, b.x, d);
                d = fmaf(a.y, b.y, d);
                d = fmaf(a.z, b.z, d);
                d = fmaf(a.w, b.w, d);
            }
            float t1 = __fadd_rn(xsq[rowBase + row], wsq[c]);
            float s = __fsub_rn(t1, __fadd_rn(d, d));
            unsigned long long key =
                ((unsigned long long)__float_as_uint(s) << 32) | (unsigned)c;
            atomicMin(best64g + rowBase + row, key);   // s>0: bit order = float order
        }
    }

    // ---- overflow fallback: ALL 512 threads cooperate per overflowed row.
    //      8 codes/thread as 2 concurrent chains; each chain is the
    //      bit-identical serial fmaf order => identical keys ----
    #pragma unroll 1
    for (int i = 0; i < ovf_n; ++i) {
        const int row = ovf_list[i];
        const float* xr = x + (size_t)(rowBase + row) * DIM;
        const float xq = xsq[rowBase + row];
        unsigned long long best = 0xFFFFFFFFFFFFFFFFULL;
        #pragma unroll 1
        for (int t0 = tid; t0 < CPB; t0 += 1024) {     // codes t0 and t0+512
            int ca = codeBase + t0;
            int cb = codeBase + t0 + 512;
            const float* wa = w + (size_t)ca * DIM;
            const float* wb = w + (size_t)cb * DIM;
            float da = 0.f, db = 0.f;
            #pragma unroll
            for (int k = 0; k < DIM; k += 4) {
                float4 av  = *reinterpret_cast<const float4*>(xr + k);
                float4 b4a = *reinterpret_cast<const float4*>(wa + k);
                float4 b4b = *reinterpret_cast<const float4*>(wb + k);
                da = fmaf(av.x, b4a.x, da); da = fmaf(av.y, b4a.y, da);
                da = fmaf(av.z, b4a.z, da); da = fmaf(av.w, b4a.w, da);
                db = fmaf(av.x, b4b.x, db); db = fmaf(av.y, b4b.y, db);
                db = fmaf(av.z, b4b.z, db); db = fmaf(av.w, b4b.w, db);
            }
            float sa = __fsub_rn(__fadd_rn(xq, wsq[ca]), __fadd_rn(da, da));
            float sb = __fsub_rn(__fadd_rn(xq, wsq[cb]), __fadd_rn(db, db));
            unsigned long long ka =
                ((unsigned long long)__float_as_uint(sa) << 32) | (unsigned)ca;
            unsigned long long kb =
                ((unsigned long long)__float_as_uint(sb) << 32) | (unsigned)cb;
            best = best < ka ? best : ka;
            best = best < kb ? best : kb;
        }
        #pragma unroll
        for (int msk = 32; msk >= 1; msk >>= 1) {
            unsigned long long o = __shfl_xor(best, msk, 64);
            best = best < o ? best : o;
        }
        if (lane == 0) atomicMin(best64g + rowBase + row, best);
    }
}

// Final: read per-row best key, write index + gather codeword.
__global__ __launch_bounds__(256)
void out_kernel(const float* __restrict__ w,
                const unsigned long long* __restrict__ best64g,
                float* __restrict__ out_q, float* __restrict__ out_idx) {
    int r = blockIdx.x * 4 + (threadIdx.x >> 6);
    int lane = threadIdx.x & 63;
    unsigned long long key = best64g[r];
    int idx = (int)(key & 0xFFFFFFFFu);
    float4 v = reinterpret_cast<const float4*>(w + (size_t)idx * DIM)[lane];
    reinterpret_cast<float4*>(out_q + (size_t)r * DIM)[lane] = v;
    if (lane == 0) out_idx[r] = (float)idx;
}

extern "C" void kernel_launch(void* const* d_in, const int* in_sizes, int n_in,
                              void* d_out, int out_size, void* d_ws, size_t ws_size,
                              hipStream_t stream) {
    const float* x = (const float*)d_in[0];   // (16384, 256) fp32
    const float* w = (const float*)d_in[1];   // (8192, 256) fp32
    float* out_q = (float*)d_out;
    float* out_idx = (float*)d_out + (size_t)NROWS * DIM;

    unsigned short* whf = (unsigned short*)d_ws;                      // 4 MB
    float* wsq = (float*)((char*)d_ws + (size_t)NCODES * DIM * 2);    // 32 KB
    float* xsq = wsq + NCODES;                                        // 64 KB
    unsigned long long* best64g = (unsigned long long*)(xsq + NROWS); // 128 KB

    prep_kernel<<<WFRAG_BLOCKS + SQ_BLOCKS, 256, 0, stream>>>(x, w, whf, xsq, wsq, best64g);
    vq_main<<<(NROWS / BM) * SPLITS, 512, 0, stream>>>(x, w, whf, wsq, xsq, best64g);
    out_kernel<<<NROWS / 4, 256, 0, stream>>>(w, best64g, out_q, out_idx);
}